// Round 12
// baseline (330.468 us; speedup 1.0000x reference)
//
#include <hip/hip_runtime.h>

// OverISS-T  (input (2,4,512,1000) complex, 5 iterations)
// Multi-kernel, stream-ordered. Y state lives in d_out (Yr | Yi planes, final
// output layout). W/H are dead state w.r.t. Y — skipped.
//
// Round 12 = Round 11 + boundary fix: the standalone tap-4 window must
// clamp+zero m<0 at slot s==0 (wave-0 lanes 0-1 read m=-2,-1). R11 read
// out-of-bounds LDS there unmasked -> absmax 0.98.
//  - dereverb TAP-PAIR FUSION: taps (0,1),(2,3) share ONE reduction round.
//    Exact: cross_c = Σ w_c z_a conj(z_b); num'^b = num^b − v^a⊗cross.
//    16 rounds/iter vs 24.
//  - Y global loads issued at kernel entry (latency hidden under g-reduce).

constexpr int NCH = 4;
constexpr int NFQ = 512;
constexpr int NFR = 1000;
constexpr int NIT = 5;
constexpr float EPSV  = 1e-3f;
constexpr float INVNF = 1.0f / 1000.0f;
constexpr float INVFN = 1.0f / (512.0f * 1000.0f);
constexpr size_t PLANE = 4096000;             // 2*4*512*1000
constexpr size_t CSTRIDE = (size_t)NFQ * NFR; // 512000

typedef float f2 __attribute__((ext_vector_type(2)));

__device__ __forceinline__ float fast_rcp(float x) { return __builtin_amdgcn_rcpf(x); }
__device__ __forceinline__ float fast_rsq(float x) { return __builtin_amdgcn_rsqf(x); }

template <int CTRL>
__device__ __forceinline__ float dpp_add(float x) {
  return x + __int_as_float(__builtin_amdgcn_update_dpp(
      0, __float_as_int(x), CTRL, 0xF, 0xF, true));
}
__device__ __forceinline__ float wave_red(float x) {
  x = dpp_add<0xB1>(x);    // quad_perm [1,0,3,2]
  x = dpp_add<0x4E>(x);    // quad_perm [2,3,0,1]
  x = dpp_add<0x141>(x);   // row_half_mirror
  x = dpp_add<0x140>(x);   // row_mirror
  x = dpp_add<0x142>(x);   // row_bcast15
  x = dpp_add<0x143>(x);   // row_bcast31
  return __int_as_float(__builtin_amdgcn_readlane(__float_as_int(x), 63));
}

// u = y * conj(z):  u.lo = yr*zr + yi*zi ; u.hi = yi*zr - yr*zi   (2 VOP3P)
__device__ __forceinline__ f2 cmulconj(f2 y, f2 z) {
  f2 t, u;
  asm("v_pk_mul_f32 %0, %1, %2 op_sel:[1,1] op_sel_hi:[0,1] neg_hi:[1,0]"
      : "=v"(t) : "v"(y), "v"(z));
  asm("v_pk_fma_f32 %0, %1, %2, %3 op_sel_hi:[1,0,1]"
      : "=v"(u) : "v"(y), "v"(z), "v"(t));
  return u;
}
// p += w * u   (w broadcast from lo lane)
__device__ __forceinline__ void pk_acc(f2& p, f2 w2, f2 u) {
  asm("v_pk_fma_f32 %0, %1, %2, %0 op_sel_hi:[0,1,1]"
      : "+v"(p) : "v"(w2), "v"(u));
}
// y -= v*z (complex)
__device__ __forceinline__ void cupdate(f2& y, f2 v, f2 z) {
  asm("v_pk_fma_f32 %0, %1, %2, %0 op_sel_hi:[0,1,1] neg_lo:[1,0,0] neg_hi:[1,0,0]"
      : "+v"(y) : "v"(v), "v"(z));
  asm("v_pk_fma_f32 %0, %1, %2, %0 op_sel:[1,1,0] op_sel_hi:[1,0,1] neg_hi:[1,0,0]"
      : "+v"(y) : "v"(v), "v"(z));
}

// ---- Y0 = 0.999*X[c] + 0.001*sum_d X[d];  optional |Y0|^2 plane ----
__global__ __launch_bounds__(256, 4)
void init_y(const float* __restrict__ Xr, const float* __restrict__ Xi,
            float* __restrict__ Y, float* __restrict__ mag)
{
  const int bf = blockIdx.x, b = bf >> 9, f = bf & 511;
  const size_t base = ((size_t)b * NCH * NFQ + f) * NFR;
  const int tid = threadIdx.x;
  if (tid < 250) {
    const int nq = 4 * tid;
    float4 xr[4], xi[4];
    #pragma unroll
    for (int c = 0; c < 4; ++c) {
      xr[c] = *(const float4*)(Xr + base + (size_t)c * CSTRIDE + nq);
      xi[c] = *(const float4*)(Xi + base + (size_t)c * CSTRIDE + nq);
    }
    float4 sr, si;
    sr.x = xr[0].x+xr[1].x+xr[2].x+xr[3].x;  si.x = xi[0].x+xi[1].x+xi[2].x+xi[3].x;
    sr.y = xr[0].y+xr[1].y+xr[2].y+xr[3].y;  si.y = xi[0].y+xi[1].y+xi[2].y+xi[3].y;
    sr.z = xr[0].z+xr[1].z+xr[2].z+xr[3].z;  si.z = xi[0].z+xi[1].z+xi[2].z+xi[3].z;
    sr.w = xr[0].w+xr[1].w+xr[2].w+xr[3].w;  si.w = xi[0].w+xi[1].w+xi[2].w+xi[3].w;
    #pragma unroll
    for (int c = 0; c < 4; ++c) {
      float4 yr, yi;
      yr.x = 0.999f*xr[c].x + 0.001f*sr.x;  yi.x = 0.999f*xi[c].x + 0.001f*si.x;
      yr.y = 0.999f*xr[c].y + 0.001f*sr.y;  yi.y = 0.999f*xi[c].y + 0.001f*si.y;
      yr.z = 0.999f*xr[c].z + 0.001f*sr.z;  yi.z = 0.999f*xi[c].z + 0.001f*si.z;
      yr.w = 0.999f*xr[c].w + 0.001f*sr.w;  yi.w = 0.999f*xi[c].w + 0.001f*si.w;
      *(float4*)(Y + base + (size_t)c * CSTRIDE + nq)         = yr;
      *(float4*)(Y + base + (size_t)c * CSTRIDE + nq + PLANE) = yi;
      if (mag) {
        float4 m;
        m.x = yr.x*yr.x + yi.x*yi.x;  m.y = yr.y*yr.y + yi.y*yi.y;
        m.z = yr.z*yr.z + yi.z*yi.z;  m.w = yr.w*yr.w + yi.w*yi.w;
        *(float4*)(mag + base + (size_t)c * CSTRIDE + nq) = m;
      }
    }
  }
}

// ---- mag reduction over f, stage 1: 32-f chunks (128 blocks) ----
__global__ __launch_bounds__(256, 4)
void partial_mag(const float* __restrict__ mag, float* __restrict__ part2)
{
  const int id = blockIdx.x;                  // b | c | k
  const int k = id & 15, c = (id >> 4) & 3, b = id >> 6;
  const int tid = threadIdx.x;
  if (tid < 250) {
    const int nq = 4 * tid;
    const float* base = mag + ((size_t)((b*4+c)*NFQ + k*32)) * NFR + nq;
    float4 acc = make_float4(0.f, 0.f, 0.f, 0.f);
    for (int ff = 0; ff < 32; ++ff) {
      const float4 v = *(const float4*)(base + (size_t)ff * NFR);
      acc.x += v.x; acc.y += v.y; acc.z += v.z; acc.w += v.w;
    }
    *(float4*)(part2 + ((size_t)((b*4+c)*16 + k)) * NFR + nq) = acc;
  }
}

// ---- mag reduction stage 2 ----
__global__ __launch_bounds__(256, 4)
void finish_mag(const float* __restrict__ part2, float* __restrict__ sumf)
{
  const int t = blockIdx.x * 256 + threadIdx.x;   // 8 blocks, 2000 quads
  if (t < 2000) {
    const int b = t / 1000, r = t - 1000 * b;
    const int c = r / 250,  qn = r - 250 * c;
    const float* base = part2 + ((size_t)((b*4+c)*16)) * NFR + 4*qn;
    float4 acc = make_float4(0.f, 0.f, 0.f, 0.f);
    #pragma unroll
    for (int k = 0; k < 16; ++k) {
      const float4 v = *(const float4*)(base + (size_t)k * NFR);
      acc.x += v.x; acc.y += v.y; acc.z += v.z; acc.w += v.w;
    }
    *(float4*)(sumf + (size_t)b*4000 + c*1000 + 4*qn) = acc;
  }
}

// ---- legacy sumf path (reads Y) — fallback when ws is small ----
__global__ __launch_bounds__(256, 4)
void partial_sumf(const float* __restrict__ Y, float* __restrict__ part)
{
  const int id = blockIdx.x;                 // b | c | q
  const int q = id & 31, c = (id >> 5) & 3, b = id >> 7;
  const size_t base = (size_t)(b * NCH + c) * CSTRIDE + (size_t)q * 16 * NFR;
  float acc[4] = {0.f, 0.f, 0.f, 0.f};
  for (int ff = 0; ff < 16; ++ff) {
    #pragma unroll
    for (int k = 0; k < 4; ++k) {
      const int n = threadIdx.x + 256 * k;
      if (n < NFR) {
        const float r = Y[base + (size_t)ff * NFR + n];
        const float i = Y[base + (size_t)ff * NFR + n + PLANE];
        acc[k] = fmaf(r, r, acc[k]);
        acc[k] = fmaf(i, i, acc[k]);
      }
    }
  }
  #pragma unroll
  for (int k = 0; k < 4; ++k) {
    const int n = threadIdx.x + 256 * k;
    if (n < NFR) part[((size_t)(b * NCH + c) * 32 + q) * NFR + n] = acc[k];
  }
}
__global__ __launch_bounds__(256, 4)
void finish_sumf(const float* __restrict__ part, float* __restrict__ sumf)
{
  const int o = blockIdx.x * 256 + threadIdx.x;
  if (o < 8000) {
    const int b = o / 4000;
    const int rem = o - b * 4000;
    const int c = rem / 1000;
    const int n = rem - c * 1000;
    const float* p = part + ((size_t)(b * NCH + c) * 32) * NFR + n;
    float s = 0.f;
    for (int q = 0; q < 32; ++q) s += p[(size_t)q * NFR];
    sumf[o] = s;
  }
}

// ---- stage C: one full iteration for one (b,f) slice — TWO waves, packed ----
// wave wid owns slots s=0..7: frame n = 512*wid + 64*s + lane
__global__ __launch_bounds__(128, 2)
void iter_c(const float* __restrict__ Xr, const float* __restrict__ Xi,
            float* __restrict__ Y, const float* __restrict__ sumf,
            float* __restrict__ mag)
{
  __shared__ f2 x2[NCH][NFR];        // interleaved ⟨re,im⟩, 32 KB
  __shared__ float red32[2][2][32];  // [parity][wave][up to 32]
  __shared__ float gred[2][4];

  const int tid  = threadIdx.x;
  const int lane = tid & 63;
  const int wid  = tid >> 6;
  const int ow   = wid ^ 1;
  const int bf   = blockIdx.x, b = bf >> 9, f = bf & 511;
  const size_t base = ((size_t)b * NCH * NFQ + f) * NFR;
  const int nb = 512 * wid + lane;          // frame of slot 0

  // ---- issue Y loads FIRST (latency hides under sumf reduce + barrier) ----
  f2 y2[8][4];
  #pragma unroll
  for (int s = 0; s < 8; ++s) {
    const int na = min(nb + 64*s, 999);
    #pragma unroll
    for (int c = 0; c < 4; ++c) {
      f2 t;
      t.x = Y[base + (size_t)c*CSTRIDE + na];
      t.y = Y[base + (size_t)c*CSTRIDE + na + PLANE];
      y2[s][c] = t;
    }
  }

  // ---- stage X into LDS interleaved ----
  for (int j = tid; j < NCH * 250; j += 128) {
    const int c = j / 250, q = j - c * 250;
    const float4 vr = *(const float4*)(Xr + base + (size_t)c*CSTRIDE + 4*q);
    const float4 vi = *(const float4*)(Xi + base + (size_t)c*CSTRIDE + 4*q);
    *(float4*)(&x2[c][4*q])     = make_float4(vr.x, vi.x, vr.y, vi.y);
    *(float4*)(&x2[c][4*q + 2]) = make_float4(vr.z, vi.z, vr.w, vi.w);
  }

  // ---- sumf -> g (cross-wave via gred), invgs, weights w ----
  float w[8][4], invgs[4];
  {
    float sfr[8][4];
    const float* sfb = sumf + b * 4000;
    #pragma unroll
    for (int s = 0; s < 8; ++s) {
      const int na = min(nb + 64*s, 999);
      #pragma unroll
      for (int c = 0; c < 4; ++c) sfr[s][c] = sfb[c*1000 + na];
    }
    float gp[4] = {0.f, 0.f, 0.f, 0.f};
    #pragma unroll
    for (int s = 0; s < 8; ++s) {
      const bool valid = (nb + 64*s) < NFR;
      #pragma unroll
      for (int c = 0; c < 4; ++c) gp[c] += valid ? sfr[s][c] : 0.f;
    }
    #pragma unroll
    for (int c = 0; c < 4; ++c) gp[c] = wave_red(gp[c]);
    if (lane == 0) {
      #pragma unroll
      for (int c = 0; c < 4; ++c) gred[wid][c] = gp[c];
    }
    __syncthreads();                        // also orders X staging

    #pragma unroll
    for (int c = 0; c < 4; ++c) {
      const float g = fmaxf((gred[0][c] + gred[1][c]) * INVFN, EPSV);
      invgs[c] = fast_rsq(g);               // sqrt(g) >= sqrt(1e-3) > EPS
      #pragma unroll
      for (int s = 0; s < 8; ++s) {
        const bool valid = (nb + 64*s) < NFR;
        w[s][c] = valid ? g * fminf(0.5f * fast_rsq(sfr[s][c]), 1e5f) : 0.f;
      }
    }
  }

  // ---- normalize Y ----
  #pragma unroll
  for (int s = 0; s < 8; ++s) {
    #pragma unroll
    for (int c = 0; c < 4; ++c) {
      y2[s][c].x *= invgs[c];
      y2[s][c].y *= invgs[c];
    }
  }

  int par = 0;

  // ----- 4 source stages (sequential; z = y[.][src]) -----
  #pragma unroll
  for (int src = 0; src < 4; ++src) {
    f2 p2[4]; float pd[4];
    #pragma unroll
    for (int c = 0; c < 4; ++c) { p2[c] = (f2){0.f, 0.f}; pd[c] = 0.f; }
    #pragma unroll
    for (int s = 0; s < 8; ++s) {
      const f2 z = y2[s][src];
      const float zz = z.x*z.x + z.y*z.y;
      #pragma unroll
      for (int c = 0; c < 4; ++c) {
        const float wk = w[s][c];
        pd[c] = fmaf(wk, zz, pd[c]);
        if (c != src) {
          const f2 u = cmulconj(y2[s][c], z);
          f2 w2; w2.x = wk; w2.y = wk;
          pk_acc(p2[c], w2, u);
        }
      }
    }
    #pragma unroll
    for (int c = 0; c < 4; ++c) {
      pd[c] = wave_red(pd[c]);
      if (c != src) { p2[c].x = wave_red(p2[c].x); p2[c].y = wave_red(p2[c].y); }
    }
    if (lane == 0) {
      #pragma unroll
      for (int c = 0; c < 4; ++c) {
        red32[par][wid][c]     = p2[c].x;
        red32[par][wid][4 + c] = p2[c].y;
        red32[par][wid][8 + c] = pd[c];
      }
    }
    __syncthreads();
    #pragma unroll
    for (int c = 0; c < 4; ++c) {
      p2[c].x += red32[par][ow][c];
      p2[c].y += red32[par][ow][4 + c];
      pd[c]   += red32[par][ow][8 + c];
    }
    par ^= 1;

    f2 vp[4];
    #pragma unroll
    for (int c = 0; c < 4; ++c) {
      const float vd  = fmaxf(pd[c] * INVNF, EPSV);
      const float inv = INVNF * fast_rcp(vd);
      vp[c].x = p2[c].x * inv;  vp[c].y = p2[c].y * inv;
    }
    vp[src].x = 1.0f - fast_rsq(fmaxf(pd[src] * INVNF, EPSV));
    vp[src].y = 0.0f;

    #pragma unroll
    for (int s = 0; s < 8; ++s) {
      const f2 z = y2[s][src];            // copy before in-place updates
      #pragma unroll
      for (int c = 0; c < 4; ++c) cupdate(y2[s][c], vp[c], z);
    }
  }

  // ----- dereverb: per src, 2 fused tap-pairs + 1 single tap -----
  for (int src = 0; src < 4; ++src) {
    // --- pairs (0,1) and (2,3) ---
    #pragma unroll
    for (int pr = 0; pr < 2; ++pr) {
      // load pair tap windows: xwp[s][j] = X[src][nb + 64s - 6 + 2*pr + j]
      f2 xwp[8][2];
      #pragma unroll
      for (int s = 0; s < 8; ++s) {
        #pragma unroll
        for (int j = 0; j < 2; ++j) {
          const int m = nb + 64*s - 6 + 2*pr + j;
          int mc = m;
          if (s == 0) mc = max(m, 0);
          if (s == 7) mc = min(m, 999);
          f2 v = x2[src][mc];
          if (s == 0 && m < 0) v = (f2){0.f, 0.f};
          xwp[s][j] = v;                   // n>=NFR slots masked by w=0
        }
      }

      f2 p2a[4], p2b[4], px[4]; float pda[4], pdb[4];
      #pragma unroll
      for (int c = 0; c < 4; ++c) {
        p2a[c] = (f2){0.f,0.f}; p2b[c] = (f2){0.f,0.f}; px[c] = (f2){0.f,0.f};
        pda[c] = 0.f; pdb[c] = 0.f;
      }
      #pragma unroll
      for (int s = 0; s < 8; ++s) {
        const f2 za = xwp[s][0], zb = xwp[s][1];
        const float zza = za.x*za.x + za.y*za.y;
        const float zzb = zb.x*zb.x + zb.y*zb.y;
        const f2 cab = cmulconj(za, zb);     // z_a * conj(z_b)
        #pragma unroll
        for (int c = 0; c < 4; ++c) {
          const float wk = w[s][c];
          f2 w2; w2.x = wk; w2.y = wk;
          pda[c] = fmaf(wk, zza, pda[c]);
          pdb[c] = fmaf(wk, zzb, pdb[c]);
          const f2 ua = cmulconj(y2[s][c], za);
          pk_acc(p2a[c], w2, ua);
          const f2 ub = cmulconj(y2[s][c], zb);
          pk_acc(p2b[c], w2, ub);
          pk_acc(px[c], w2, cab);
        }
      }

      float rv[32];
      #pragma unroll
      for (int c = 0; c < 4; ++c) {
        rv[c]      = p2a[c].x;  rv[4+c]  = p2a[c].y;  rv[8+c]  = pda[c];
        rv[12+c]   = p2b[c].x;  rv[16+c] = p2b[c].y;  rv[20+c] = pdb[c];
        rv[24+c]   = px[c].x;   rv[28+c] = px[c].y;
      }
      #pragma unroll
      for (int j = 0; j < 32; ++j) rv[j] = wave_red(rv[j]);
      if (lane == 0) {
        #pragma unroll
        for (int j = 0; j < 32; ++j) red32[par][wid][j] = rv[j];
      }
      __syncthreads();
      #pragma unroll
      for (int j = 0; j < 32; ++j) rv[j] += red32[par][ow][j];
      par ^= 1;

      f2 va[4], vb[4];
      #pragma unroll
      for (int c = 0; c < 4; ++c) {        // dereverb: no inv_nf (matches ref)
        const float inva = fast_rcp(fmaxf(rv[8+c], EPSV));
        const float var = rv[c] * inva, vai = rv[4+c] * inva;
        const float cxr = rv[24+c], cxi = rv[28+c];
        // num'^b = num^b − v^a ⊗ cross   (full complex product)
        const float nbr = rv[12+c] - (var*cxr - vai*cxi);
        const float nbi = rv[16+c] - (var*cxi + vai*cxr);
        const float invb = fast_rcp(fmaxf(rv[20+c], EPSV));
        va[c].x = var;        va[c].y = vai;
        vb[c].x = nbr * invb; vb[c].y = nbi * invb;
      }
      #pragma unroll
      for (int s = 0; s < 8; ++s) {
        const f2 za = xwp[s][0], zb = xwp[s][1];
        #pragma unroll
        for (int c = 0; c < 4; ++c) {
          cupdate(y2[s][c], va[c], za);
          cupdate(y2[s][c], vb[c], zb);
        }
      }
    }

    // --- single tap 4 (off = -2; m<0 possible for wave-0 lanes 0-1 at s=0) ---
    {
      f2 xw4[8];
      #pragma unroll
      for (int s = 0; s < 8; ++s) {
        const int m = nb + 64*s - 2;
        int mc = m;
        if (s == 0) mc = max(m, 0);
        if (s == 7) mc = min(m, 999);
        f2 v = x2[src][mc];
        if (s == 0 && m < 0) v = (f2){0.f, 0.f};   // pre-signal taps are zero
        xw4[s] = v;
      }
      f2 p2[4]; float pd[4];
      #pragma unroll
      for (int c = 0; c < 4; ++c) { p2[c] = (f2){0.f,0.f}; pd[c] = 0.f; }
      #pragma unroll
      for (int s = 0; s < 8; ++s) {
        const f2 z = xw4[s];
        const float zz = z.x*z.x + z.y*z.y;
        #pragma unroll
        for (int c = 0; c < 4; ++c) {
          const float wk = w[s][c];
          f2 w2; w2.x = wk; w2.y = wk;
          pd[c] = fmaf(wk, zz, pd[c]);
          const f2 u = cmulconj(y2[s][c], z);
          pk_acc(p2[c], w2, u);
        }
      }
      #pragma unroll
      for (int c = 0; c < 4; ++c) {
        p2[c].x = wave_red(p2[c].x);
        p2[c].y = wave_red(p2[c].y);
        pd[c]   = wave_red(pd[c]);
      }
      if (lane == 0) {
        #pragma unroll
        for (int c = 0; c < 4; ++c) {
          red32[par][wid][c]     = p2[c].x;
          red32[par][wid][4 + c] = p2[c].y;
          red32[par][wid][8 + c] = pd[c];
        }
      }
      __syncthreads();
      #pragma unroll
      for (int c = 0; c < 4; ++c) {
        p2[c].x += red32[par][ow][c];
        p2[c].y += red32[par][ow][4 + c];
        pd[c]   += red32[par][ow][8 + c];
      }
      par ^= 1;

      f2 vp[4];
      #pragma unroll
      for (int c = 0; c < 4; ++c) {
        const float inv = fast_rcp(fmaxf(pd[c], EPSV));
        vp[c].x = p2[c].x * inv;  vp[c].y = p2[c].y * inv;
      }
      #pragma unroll
      for (int s = 0; s < 8; ++s) {
        const f2 z = xw4[s];
        #pragma unroll
        for (int c = 0; c < 4; ++c) cupdate(y2[s][c], vp[c], z);
      }
    }
  }

  // ---- write back Y (+ optional |Y|^2 plane) ----
  #pragma unroll
  for (int s = 0; s < 8; ++s) {
    const int n = nb + 64*s;
    if (n < NFR) {
      #pragma unroll
      for (int c = 0; c < 4; ++c) {
        const float yr = y2[s][c].x, yi = y2[s][c].y;
        Y[base + (size_t)c*CSTRIDE + n]         = yr;
        Y[base + (size_t)c*CSTRIDE + n + PLANE] = yi;
        if (mag) mag[base + (size_t)c*CSTRIDE + n] = yr*yr + yi*yi;
      }
    }
  }
}

extern "C" void kernel_launch(void* const* d_in, const int* in_sizes, int n_in,
                              void* d_out, int out_size, void* d_ws, size_t ws_size,
                              hipStream_t stream)
{
  const float* Xr = (const float*)d_in[0];
  const float* Xi = (const float*)d_in[1];
  float* Y = (float*)d_out;                 // Yr | Yi, final layout

  const bool big_ws = ws_size >= (size_t)(4096000 + 128000 + 8000) * 4;
  if (big_ws) {
    float* mag   = (float*)d_ws;            // 4,096,000 floats
    float* part2 = mag + 4096000;           // 128,000
    float* sumf  = part2 + 128000;          // 8,000
    init_y<<<1024, 256, 0, stream>>>(Xr, Xi, Y, mag);
    for (int it = 0; it < NIT; ++it) {
      partial_mag<<<128, 256, 0, stream>>>(mag, part2);
      finish_mag<<<8, 256, 0, stream>>>(part2, sumf);
      iter_c<<<1024, 128, 0, stream>>>(Xr, Xi, Y, sumf,
                                       (it < NIT - 1) ? mag : nullptr);
    }
  } else {
    float* part = (float*)d_ws;             // 256,000 floats
    float* sumf = part + 256000;            // 8,000
    init_y<<<1024, 256, 0, stream>>>(Xr, Xi, Y, nullptr);
    for (int it = 0; it < NIT; ++it) {
      partial_sumf<<<256, 256, 0, stream>>>(Y, part);
      finish_sumf<<<32, 256, 0, stream>>>(part, sumf);
      iter_c<<<1024, 128, 0, stream>>>(Xr, Xi, Y, sumf, nullptr);
    }
  }
}

// Round 13
// 305.011 us; speedup vs baseline: 1.0835x; 1.0835x over previous
//
#include <hip/hip_runtime.h>

// OverISS-T  (input (2,4,512,1000) complex, 5 iterations)
// Multi-kernel, stream-ordered. Y state lives in d_out (Yr | Yi planes, final
// output layout). W/H are dead state w.r.t. Y — skipped.
//
// Round 13 = exact revert to Round 10 (best measured: 305 us).
// R10: packed dual-FP32 (v_pk_fma_f32 / v_pk_mul_f32) for the complex
// accumulate (y*conj(z)), the rank-1 update, and weight application.
// X staged INTERLEAVED <re,im> in LDS so tap windows load as ds_read_b64
// straight into packed register pairs. 2-wave blocks (8 slots/thread),
// DPP wave reductions, one barrier per stage, mag-plane sumf pipeline.
// Measured evidence for this being the structure's optimum:
//  - R9 (4-wave): per-stage tail duplicated -> +31% issue, slower.
//  - R12 (tap-pair fusion, 16 barriers instead of 24): slower by the added
//    issue cost -> barriers already hidden by co-resident blocks.

constexpr int NCH = 4;
constexpr int NFQ = 512;
constexpr int NFR = 1000;
constexpr int NIT = 5;
constexpr float EPSV  = 1e-3f;
constexpr float INVNF = 1.0f / 1000.0f;
constexpr float INVFN = 1.0f / (512.0f * 1000.0f);
constexpr size_t PLANE = 4096000;             // 2*4*512*1000
constexpr size_t CSTRIDE = (size_t)NFQ * NFR; // 512000

typedef float f2 __attribute__((ext_vector_type(2)));

__device__ __forceinline__ float fast_rcp(float x) { return __builtin_amdgcn_rcpf(x); }
__device__ __forceinline__ float fast_rsq(float x) { return __builtin_amdgcn_rsqf(x); }

template <int CTRL>
__device__ __forceinline__ float dpp_add(float x) {
  return x + __int_as_float(__builtin_amdgcn_update_dpp(
      0, __float_as_int(x), CTRL, 0xF, 0xF, true));
}
__device__ __forceinline__ float wave_red(float x) {
  x = dpp_add<0xB1>(x);    // quad_perm [1,0,3,2]
  x = dpp_add<0x4E>(x);    // quad_perm [2,3,0,1]
  x = dpp_add<0x141>(x);   // row_half_mirror
  x = dpp_add<0x140>(x);   // row_mirror
  x = dpp_add<0x142>(x);   // row_bcast15
  x = dpp_add<0x143>(x);   // row_bcast31
  return __int_as_float(__builtin_amdgcn_readlane(__float_as_int(x), 63));
}

// u = y * conj(z):  u.lo = yr*zr + yi*zi ; u.hi = yi*zr - yr*zi   (2 VOP3P)
__device__ __forceinline__ f2 cmulconj(f2 y, f2 z) {
  f2 t, u;
  asm("v_pk_mul_f32 %0, %1, %2 op_sel:[1,1] op_sel_hi:[0,1] neg_hi:[1,0]"
      : "=v"(t) : "v"(y), "v"(z));
  // t.lo = yi*zi ; t.hi = -yr*zi
  asm("v_pk_fma_f32 %0, %1, %2, %3 op_sel_hi:[1,0,1]"
      : "=v"(u) : "v"(y), "v"(z), "v"(t));
  // u.lo = yr*zr + t.lo ; u.hi = yi*zr + t.hi
  return u;
}
// p += w * u   (w broadcast from lo lane)
__device__ __forceinline__ void pk_acc(f2& p, f2 w2, f2 u) {
  asm("v_pk_fma_f32 %0, %1, %2, %0 op_sel_hi:[0,1,1]"
      : "+v"(p) : "v"(w2), "v"(u));
}
// y -= v*z (complex):  y.lo -= vr*zr - vi*zi ; y.hi -= vr*zi + vi*zr
__device__ __forceinline__ void cupdate(f2& y, f2 v, f2 z) {
  asm("v_pk_fma_f32 %0, %1, %2, %0 op_sel_hi:[0,1,1] neg_lo:[1,0,0] neg_hi:[1,0,0]"
      : "+v"(y) : "v"(v), "v"(z));   // y += (-vr)*<zr,zi>
  asm("v_pk_fma_f32 %0, %1, %2, %0 op_sel:[1,1,0] op_sel_hi:[1,0,1] neg_hi:[1,0,0]"
      : "+v"(y) : "v"(v), "v"(z));   // y.lo += vi*zi ; y.hi += -vi*zr
}

// ---- Y0 = 0.999*X[c] + 0.001*sum_d X[d];  optional |Y0|^2 plane ----
__global__ __launch_bounds__(256, 4)
void init_y(const float* __restrict__ Xr, const float* __restrict__ Xi,
            float* __restrict__ Y, float* __restrict__ mag)
{
  const int bf = blockIdx.x, b = bf >> 9, f = bf & 511;
  const size_t base = ((size_t)b * NCH * NFQ + f) * NFR;
  const int tid = threadIdx.x;
  if (tid < 250) {
    const int nq = 4 * tid;
    float4 xr[4], xi[4];
    #pragma unroll
    for (int c = 0; c < 4; ++c) {
      xr[c] = *(const float4*)(Xr + base + (size_t)c * CSTRIDE + nq);
      xi[c] = *(const float4*)(Xi + base + (size_t)c * CSTRIDE + nq);
    }
    float4 sr, si;
    sr.x = xr[0].x+xr[1].x+xr[2].x+xr[3].x;  si.x = xi[0].x+xi[1].x+xi[2].x+xi[3].x;
    sr.y = xr[0].y+xr[1].y+xr[2].y+xr[3].y;  si.y = xi[0].y+xi[1].y+xi[2].y+xi[3].y;
    sr.z = xr[0].z+xr[1].z+xr[2].z+xr[3].z;  si.z = xi[0].z+xi[1].z+xi[2].z+xi[3].z;
    sr.w = xr[0].w+xr[1].w+xr[2].w+xr[3].w;  si.w = xi[0].w+xi[1].w+xi[2].w+xi[3].w;
    #pragma unroll
    for (int c = 0; c < 4; ++c) {
      float4 yr, yi;
      yr.x = 0.999f*xr[c].x + 0.001f*sr.x;  yi.x = 0.999f*xi[c].x + 0.001f*si.x;
      yr.y = 0.999f*xr[c].y + 0.001f*sr.y;  yi.y = 0.999f*xi[c].y + 0.001f*si.y;
      yr.z = 0.999f*xr[c].z + 0.001f*sr.z;  yi.z = 0.999f*xi[c].z + 0.001f*si.z;
      yr.w = 0.999f*xr[c].w + 0.001f*sr.w;  yi.w = 0.999f*xi[c].w + 0.001f*si.w;
      *(float4*)(Y + base + (size_t)c * CSTRIDE + nq)         = yr;
      *(float4*)(Y + base + (size_t)c * CSTRIDE + nq + PLANE) = yi;
      if (mag) {
        float4 m;
        m.x = yr.x*yr.x + yi.x*yi.x;  m.y = yr.y*yr.y + yi.y*yi.y;
        m.z = yr.z*yr.z + yi.z*yi.z;  m.w = yr.w*yr.w + yi.w*yi.w;
        *(float4*)(mag + base + (size_t)c * CSTRIDE + nq) = m;
      }
    }
  }
}

// ---- mag reduction over f, stage 1: 32-f chunks (128 blocks) ----
__global__ __launch_bounds__(256, 4)
void partial_mag(const float* __restrict__ mag, float* __restrict__ part2)
{
  const int id = blockIdx.x;                  // b | c | k
  const int k = id & 15, c = (id >> 4) & 3, b = id >> 6;
  const int tid = threadIdx.x;
  if (tid < 250) {
    const int nq = 4 * tid;
    const float* base = mag + ((size_t)((b*4+c)*NFQ + k*32)) * NFR + nq;
    float4 acc = make_float4(0.f, 0.f, 0.f, 0.f);
    for (int ff = 0; ff < 32; ++ff) {
      const float4 v = *(const float4*)(base + (size_t)ff * NFR);
      acc.x += v.x; acc.y += v.y; acc.z += v.z; acc.w += v.w;
    }
    *(float4*)(part2 + ((size_t)((b*4+c)*16 + k)) * NFR + nq) = acc;
  }
}

// ---- mag reduction stage 2 ----
__global__ __launch_bounds__(256, 4)
void finish_mag(const float* __restrict__ part2, float* __restrict__ sumf)
{
  const int t = blockIdx.x * 256 + threadIdx.x;   // 8 blocks, 2000 quads
  if (t < 2000) {
    const int b = t / 1000, r = t - 1000 * b;
    const int c = r / 250,  qn = r - 250 * c;
    const float* base = part2 + ((size_t)((b*4+c)*16)) * NFR + 4*qn;
    float4 acc = make_float4(0.f, 0.f, 0.f, 0.f);
    #pragma unroll
    for (int k = 0; k < 16; ++k) {
      const float4 v = *(const float4*)(base + (size_t)k * NFR);
      acc.x += v.x; acc.y += v.y; acc.z += v.z; acc.w += v.w;
    }
    *(float4*)(sumf + (size_t)b*4000 + c*1000 + 4*qn) = acc;
  }
}

// ---- legacy sumf path (reads Y) — fallback when ws is small ----
__global__ __launch_bounds__(256, 4)
void partial_sumf(const float* __restrict__ Y, float* __restrict__ part)
{
  const int id = blockIdx.x;                 // b | c | q
  const int q = id & 31, c = (id >> 5) & 3, b = id >> 7;
  const size_t base = (size_t)(b * NCH + c) * CSTRIDE + (size_t)q * 16 * NFR;
  float acc[4] = {0.f, 0.f, 0.f, 0.f};
  for (int ff = 0; ff < 16; ++ff) {
    #pragma unroll
    for (int k = 0; k < 4; ++k) {
      const int n = threadIdx.x + 256 * k;
      if (n < NFR) {
        const float r = Y[base + (size_t)ff * NFR + n];
        const float i = Y[base + (size_t)ff * NFR + n + PLANE];
        acc[k] = fmaf(r, r, acc[k]);
        acc[k] = fmaf(i, i, acc[k]);
      }
    }
  }
  #pragma unroll
  for (int k = 0; k < 4; ++k) {
    const int n = threadIdx.x + 256 * k;
    if (n < NFR) part[((size_t)(b * NCH + c) * 32 + q) * NFR + n] = acc[k];
  }
}
__global__ __launch_bounds__(256, 4)
void finish_sumf(const float* __restrict__ part, float* __restrict__ sumf)
{
  const int o = blockIdx.x * 256 + threadIdx.x;
  if (o < 8000) {
    const int b = o / 4000;
    const int rem = o - b * 4000;
    const int c = rem / 1000;
    const int n = rem - c * 1000;
    const float* p = part + ((size_t)(b * NCH + c) * 32) * NFR + n;
    float s = 0.f;
    for (int q = 0; q < 32; ++q) s += p[(size_t)q * NFR];
    sumf[o] = s;
  }
}

// ---- stage C: one full iteration for one (b,f) slice — TWO waves, packed ----
// wave wid owns slots s=0..7: frame n = 512*wid + 64*s + lane
__global__ __launch_bounds__(128, 2)
void iter_c(const float* __restrict__ Xr, const float* __restrict__ Xi,
            float* __restrict__ Y, const float* __restrict__ sumf,
            float* __restrict__ mag)
{
  __shared__ f2 x2[NCH][NFR];        // interleaved <re,im>, 32 KB
  __shared__ float red[2][2][12];    // [parity][wave][12]
  __shared__ float gred[2][4];

  const int tid  = threadIdx.x;
  const int lane = tid & 63;
  const int wid  = tid >> 6;
  const int ow   = wid ^ 1;
  const int bf   = blockIdx.x, b = bf >> 9, f = bf & 511;
  const size_t base = ((size_t)b * NCH * NFQ + f) * NFR;
  const int nb = 512 * wid + lane;          // frame of slot 0

  // ---- stage X into LDS interleaved (2 b128 writes per 4 frames) ----
  for (int j = tid; j < NCH * 250; j += 128) {
    const int c = j / 250, q = j - c * 250;
    const float4 vr = *(const float4*)(Xr + base + (size_t)c*CSTRIDE + 4*q);
    const float4 vi = *(const float4*)(Xi + base + (size_t)c*CSTRIDE + 4*q);
    *(float4*)(&x2[c][4*q])     = make_float4(vr.x, vi.x, vr.y, vi.y);
    *(float4*)(&x2[c][4*q + 2]) = make_float4(vr.z, vi.z, vr.w, vi.w);
  }

  // ---- sumf -> g (cross-wave via gred), invgs, weights w ----
  float w[8][4], invgs[4];
  {
    float sfr[8][4];
    const float* sfb = sumf + b * 4000;
    #pragma unroll
    for (int s = 0; s < 8; ++s) {
      const int na = min(nb + 64*s, 999);
      #pragma unroll
      for (int c = 0; c < 4; ++c) sfr[s][c] = sfb[c*1000 + na];
    }
    float gp[4] = {0.f, 0.f, 0.f, 0.f};
    #pragma unroll
    for (int s = 0; s < 8; ++s) {
      const bool valid = (nb + 64*s) < NFR;
      #pragma unroll
      for (int c = 0; c < 4; ++c) gp[c] += valid ? sfr[s][c] : 0.f;
    }
    #pragma unroll
    for (int c = 0; c < 4; ++c) gp[c] = wave_red(gp[c]);
    if (lane == 0) {
      #pragma unroll
      for (int c = 0; c < 4; ++c) gred[wid][c] = gp[c];
    }
    __syncthreads();                        // also orders X staging

    #pragma unroll
    for (int c = 0; c < 4; ++c) {
      const float g = fmaxf((gred[0][c] + gred[1][c]) * INVFN, EPSV);
      invgs[c] = fast_rsq(g);               // sqrt(g) >= sqrt(1e-3) > EPS
      #pragma unroll
      for (int s = 0; s < 8; ++s) {
        const bool valid = (nb + 64*s) < NFR;
        w[s][c] = valid ? g * fminf(0.5f * fast_rsq(sfr[s][c]), 1e5f) : 0.f;
      }
    }
  }

  // ---- load Y packed, normalize ----
  f2 y2[8][4];
  #pragma unroll
  for (int s = 0; s < 8; ++s) {
    const int na = min(nb + 64*s, 999);
    #pragma unroll
    for (int c = 0; c < 4; ++c) {
      f2 t;
      t.x = Y[base + (size_t)c*CSTRIDE + na] * invgs[c];
      t.y = Y[base + (size_t)c*CSTRIDE + na + PLANE] * invgs[c];
      y2[s][c] = t;
    }
  }

  int par = 0;
  f2 p2[4]; float pd[4], vr_[4], vi_[4];

  // ----- 4 source stages -----
  #pragma unroll
  for (int src = 0; src < 4; ++src) {
    #pragma unroll
    for (int c = 0; c < 4; ++c) { p2[c] = (f2){0.f, 0.f}; pd[c] = 0.f; }
    #pragma unroll
    for (int s = 0; s < 8; ++s) {
      const f2 z = y2[s][src];
      const float zz = z.x*z.x + z.y*z.y;
      #pragma unroll
      for (int c = 0; c < 4; ++c) {
        const float wk = w[s][c];
        pd[c] = fmaf(wk, zz, pd[c]);
        if (c != src) {
          const f2 u = cmulconj(y2[s][c], z);
          f2 w2; w2.x = wk; w2.y = wk;
          pk_acc(p2[c], w2, u);
        }
      }
    }
    #pragma unroll
    for (int c = 0; c < 4; ++c) {
      pd[c] = wave_red(pd[c]);
      if (c != src) { p2[c].x = wave_red(p2[c].x); p2[c].y = wave_red(p2[c].y); }
    }
    if (lane == 0) {
      #pragma unroll
      for (int c = 0; c < 4; ++c) {
        red[par][wid][c]     = p2[c].x;
        red[par][wid][4 + c] = p2[c].y;
        red[par][wid][8 + c] = pd[c];
      }
    }
    __syncthreads();
    #pragma unroll
    for (int c = 0; c < 4; ++c) {
      p2[c].x += red[par][ow][c];
      p2[c].y += red[par][ow][4 + c];
      pd[c]   += red[par][ow][8 + c];
    }
    par ^= 1;

    f2 vp[4];
    #pragma unroll
    for (int c = 0; c < 4; ++c) {
      const float vd  = fmaxf(pd[c] * INVNF, EPSV);
      const float inv = INVNF * fast_rcp(vd);
      vr_[c] = p2[c].x * inv;  vi_[c] = p2[c].y * inv;
    }
    vr_[src] = 1.0f - fast_rsq(fmaxf(pd[src] * INVNF, EPSV));
    vi_[src] = 0.0f;
    #pragma unroll
    for (int c = 0; c < 4; ++c) { vp[c].x = vr_[c]; vp[c].y = vi_[c]; }

    #pragma unroll
    for (int s = 0; s < 8; ++s) {
      const f2 z = y2[s][src];            // copy before in-place updates
      #pragma unroll
      for (int c = 0; c < 4; ++c) cupdate(y2[s][c], vp[c], z);
    }
  }

  // ----- 20 dereverb stages via packed per-src register tap-window -----
  // xw[s][o] = X[src][nb + 64*s - 6 + o], o=0..4; tap t reads xw[s][t].
  for (int src = 0; src < 4; ++src) {
    f2 xw[8][5];
    #pragma unroll
    for (int s = 0; s < 8; ++s) {
      #pragma unroll
      for (int o = 0; o < 5; ++o) {
        const int m = nb + 64*s - 6 + o;
        int mc = m;
        if (s == 0) mc = max(m, 0);       // m<0 only possible in slot 0 (wave 0)
        if (s == 7) mc = min(m, 999);     // m>999 only possible in slot 7 (wave 1)
        f2 v = x2[src][mc];
        if (s == 0 && m < 0) v = (f2){0.f, 0.f};   // pre-signal taps are zero
        xw[s][o] = v;                      // n>=NFR slots masked by w=0
      }
    }

    #pragma unroll
    for (int tap = 0; tap < 5; ++tap) {
      #pragma unroll
      for (int c = 0; c < 4; ++c) { p2[c] = (f2){0.f, 0.f}; pd[c] = 0.f; }
      #pragma unroll
      for (int s = 0; s < 8; ++s) {
        const f2 z = xw[s][tap];
        const float zz = z.x*z.x + z.y*z.y;
        #pragma unroll
        for (int c = 0; c < 4; ++c) {
          const float wk = w[s][c];
          pd[c] = fmaf(wk, zz, pd[c]);
          const f2 u = cmulconj(y2[s][c], z);
          f2 w2; w2.x = wk; w2.y = wk;
          pk_acc(p2[c], w2, u);
        }
      }
      #pragma unroll
      for (int c = 0; c < 4; ++c) {
        p2[c].x = wave_red(p2[c].x);
        p2[c].y = wave_red(p2[c].y);
        pd[c]   = wave_red(pd[c]);
      }
      if (lane == 0) {
        #pragma unroll
        for (int c = 0; c < 4; ++c) {
          red[par][wid][c]     = p2[c].x;
          red[par][wid][4 + c] = p2[c].y;
          red[par][wid][8 + c] = pd[c];
        }
      }
      __syncthreads();
      #pragma unroll
      for (int c = 0; c < 4; ++c) {
        p2[c].x += red[par][ow][c];
        p2[c].y += red[par][ow][4 + c];
        pd[c]   += red[par][ow][8 + c];
      }
      par ^= 1;

      f2 vp[4];
      #pragma unroll
      for (int c = 0; c < 4; ++c) {        // dereverb: no inv_nf (matches ref)
        const float inv = fast_rcp(fmaxf(pd[c], EPSV));
        vp[c].x = p2[c].x * inv;  vp[c].y = p2[c].y * inv;
      }
      #pragma unroll
      for (int s = 0; s < 8; ++s) {
        const f2 z = xw[s][tap];
        #pragma unroll
        for (int c = 0; c < 4; ++c) cupdate(y2[s][c], vp[c], z);
      }
    }
  }

  // ---- write back Y (+ optional |Y|^2 plane) ----
  #pragma unroll
  for (int s = 0; s < 8; ++s) {
    const int n = nb + 64*s;
    if (n < NFR) {
      #pragma unroll
      for (int c = 0; c < 4; ++c) {
        const float yr = y2[s][c].x, yi = y2[s][c].y;
        Y[base + (size_t)c*CSTRIDE + n]         = yr;
        Y[base + (size_t)c*CSTRIDE + n + PLANE] = yi;
        if (mag) mag[base + (size_t)c*CSTRIDE + n] = yr*yr + yi*yi;
      }
    }
  }
}

extern "C" void kernel_launch(void* const* d_in, const int* in_sizes, int n_in,
                              void* d_out, int out_size, void* d_ws, size_t ws_size,
                              hipStream_t stream)
{
  const float* Xr = (const float*)d_in[0];
  const float* Xi = (const float*)d_in[1];
  float* Y = (float*)d_out;                 // Yr | Yi, final layout

  const bool big_ws = ws_size >= (size_t)(4096000 + 128000 + 8000) * 4;
  if (big_ws) {
    float* mag   = (float*)d_ws;            // 4,096,000 floats
    float* part2 = mag + 4096000;           // 128,000
    float* sumf  = part2 + 128000;          // 8,000
    init_y<<<1024, 256, 0, stream>>>(Xr, Xi, Y, mag);
    for (int it = 0; it < NIT; ++it) {
      partial_mag<<<128, 256, 0, stream>>>(mag, part2);
      finish_mag<<<8, 256, 0, stream>>>(part2, sumf);
      iter_c<<<1024, 128, 0, stream>>>(Xr, Xi, Y, sumf,
                                       (it < NIT - 1) ? mag : nullptr);
    }
  } else {
    float* part = (float*)d_ws;             // 256,000 floats
    float* sumf = part + 256000;            // 8,000
    init_y<<<1024, 256, 0, stream>>>(Xr, Xi, Y, nullptr);
    for (int it = 0; it < NIT; ++it) {
      partial_sumf<<<256, 256, 0, stream>>>(Y, part);
      finish_sumf<<<32, 256, 0, stream>>>(part, sumf);
      iter_c<<<1024, 128, 0, stream>>>(Xr, Xi, Y, sumf, nullptr);
    }
  }
}